// Round 1
// baseline (2776.523 us; speedup 1.0000x reference)
//
#include <hip/hip_runtime.h>
#include <cstddef>

#define B_TOT 32768
#define H_STEPS 256
#define HIDN 128
#define RHIDN 64

__device__ __forceinline__ float frcp(float x){ return __builtin_amdgcn_rcpf(x); }

// tanh(x) = 1 - 2/(exp(2x)+1); exp via v_exp_f32, div via v_rcp_f32.
// Saturates correctly: x>>0 -> e=inf -> 1; x<<0 -> e=0 -> -1.
__device__ __forceinline__ float fast_tanh(float x){
  float e = __expf(x + x);
  return 1.0f - 2.0f * frcp(e + 1.0f);
}

// softplus(x) = max(x,0) + log(1+exp(-|x|))  (stable, matches jax.nn.softplus)
__device__ __forceinline__ float fast_softplus(float x){
  float e = __expf(-fabsf(x));
  return fmaxf(x, 0.0f) + __logf(1.0f + e);
}

__global__ __launch_bounds__(256, 2)
void dcir_node_kernel(const float* __restrict__ gI,
                      const float* __restrict__ gT,
                      const float* __restrict__ gsoc0,
                      const float* __restrict__ gW1,
                      const float* __restrict__ gb1,
                      const float* __restrict__ gW2,
                      const float* __restrict__ gb2,
                      const float* __restrict__ gWr1,
                      const float* __restrict__ gbr1,
                      const float* __restrict__ gWr2,
                      const float* __restrict__ gbr2,
                      float* __restrict__ gV,
                      float* __restrict__ gP,
                      float* __restrict__ gS)
{
  // Per-hidden-unit packed weights, quad-interleaved so lanes q=0..3 read
  // 4 consecutive 32B slots (banks 0..31, conflict-free broadcast).
  __shared__ float4 hw[32][4][2];   // unit j = q*32+it : {W1a,W1b,b1,W2c0},{W2c1..c4}
  __shared__ float4 rw[16][4][2];   // unit u = q*16+it : {Wr1r0..r3},{Wr1r4,br1,Wr2,0}

  const int tid = threadIdx.x;
  if (tid < HIDN){
    int j = tid;
    hw[j & 31][j >> 5][0] = make_float4(gW1[j], gW1[HIDN + j], gb1[j], gW2[j*5 + 0]);
    hw[j & 31][j >> 5][1] = make_float4(gW2[j*5+1], gW2[j*5+2], gW2[j*5+3], gW2[j*5+4]);
  } else if (tid < HIDN + RHIDN){
    int u = tid - HIDN;
    rw[u & 15][u >> 4][0] = make_float4(gWr1[0*RHIDN+u], gWr1[1*RHIDN+u],
                                        gWr1[2*RHIDN+u], gWr1[3*RHIDN+u]);
    rw[u & 15][u >> 4][1] = make_float4(gWr1[4*RHIDN+u], gbr1[u], gWr2[u], 0.0f);
  }
  __syncthreads();

  const int gtid = blockIdx.x * 256 + tid;
  const int b = gtid >> 2;   // battery index: 4 consecutive lanes per battery
  const int q = gtid & 3;    // position within quad

  const float b20 = gb2[0], b21 = gb2[1], b22 = gb2[2], b23 = gb2[3], b24 = gb2[4];
  const float br2v = gbr2[0];

  float soc = gsoc0[b];
  float vc1 = 0.0f, vc2 = 0.0f;

  const float* __restrict__ Ib = gI + (size_t)b * H_STEPS;
  const float* __restrict__ Tb = gT + (size_t)b * H_STEPS;
  float* __restrict__ Vb = gV + (size_t)b * H_STEPS;
  float* __restrict__ Pb = gP + (size_t)b * H_STEPS * 5;
  float* __restrict__ Sb = gS + (size_t)b * H_STEPS * 3;

  for (int k = 0; k < H_STEPS; ++k){
    const float ik = Ib[k];
    const float tk = Tb[k];

    // ---- param head: h = tanh([soc,t]@W1 + b1); logits = h@W2 (+b2 after reduce)
    float a0=0.f, a1=0.f, a2=0.f, a3=0.f, a4=0.f;
    #pragma unroll
    for (int it = 0; it < 32; ++it){
      const float4 wa = hw[it][q][0];
      const float4 wb = hw[it][q][1];
      float arg = fmaf(soc, wa.x, fmaf(tk, wa.y, wa.z));
      float h = fast_tanh(arg);
      a0 = fmaf(h, wa.w, a0);
      a1 = fmaf(h, wb.x, a1);
      a2 = fmaf(h, wb.y, a2);
      a3 = fmaf(h, wb.z, a3);
      a4 = fmaf(h, wb.w, a4);
    }
    a0 += __shfl_xor(a0, 1, 4); a0 += __shfl_xor(a0, 2, 4);
    a1 += __shfl_xor(a1, 1, 4); a1 += __shfl_xor(a1, 2, 4);
    a2 += __shfl_xor(a2, 1, 4); a2 += __shfl_xor(a2, 2, 4);
    a3 += __shfl_xor(a3, 1, 4); a3 += __shfl_xor(a3, 2, 4);
    a4 += __shfl_xor(a4, 1, 4); a4 += __shfl_xor(a4, 2, 4);

    const float R0 = fmaf(fast_softplus(a0 + b20), 0.005f,   1e-6f);
    const float R1 = fmaf(fast_softplus(a1 + b21), 0.005f,   1e-6f);
    const float C1 = fmaf(fast_softplus(a2 + b22), 2000.0f,  1e-6f);
    const float R2 = fmaf(fast_softplus(a3 + b23), 0.005f,   1e-6f);
    const float C2 = fmaf(fast_softplus(a4 + b24), 10000.0f, 1e-6f);

    // ---- residual MLP on [vc1,vc2,soc,i,t]
    float ra = 0.0f;
    #pragma unroll
    for (int it = 0; it < 16; ++it){
      const float4 wa = rw[it][q][0];
      const float4 wb = rw[it][q][1];
      float arg = fmaf(vc1, wa.x,
                  fmaf(vc2, wa.y,
                  fmaf(soc, wa.z,
                  fmaf(ik,  wa.w,
                  fmaf(tk,  wb.x, wb.y)))));
      ra = fmaf(fast_tanh(arg), wb.z, ra);
    }
    ra += __shfl_xor(ra, 1, 4); ra += __shfl_xor(ra, 2, 4);

    const float res = (ra + br2v) * 0.01f;
    const float ocv = fmaf(1.2f, soc, 3.0f) - 0.4f * __expf(-12.0f * soc);
    const float Vp  = ocv - R0 * ik - vc1 - vc2 + res;

    // ---- outputs for step k (pre-update state), distributed over the quad
    if (q == 0){
      Vb[k] = Vp;
      Sb[k*3 + 0] = vc1;
    } else if (q == 1){
      Pb[k*5 + 0] = R0;
      Pb[k*5 + 1] = R1;
      Sb[k*3 + 1] = vc2;
    } else if (q == 2){
      Pb[k*5 + 2] = C1;
      Pb[k*5 + 3] = R2;
      Sb[k*3 + 2] = soc;
    } else {
      Pb[k*5 + 4] = C2;
    }

    // ---- RK4 on the affine ODE dvc/dt = i/C - vc/(R*C); dsoc/dt = -i/Q (const)
    const float A1 = ik * frcp(C1);
    const float A2 = ik * frcp(C2);
    const float K1 = frcp(R1 * C1);
    const float K2 = frcp(R2 * C2);

    float s1 = A1 - K1 * vc1;
    float s2 = A1 - K1 * fmaf(0.5f, s1, vc1);
    float s3 = A1 - K1 * fmaf(0.5f, s2, vc1);
    float s4 = A1 - K1 * (vc1 + s3);
    vc1 = vc1 + (1.0f/6.0f) * (s1 + 2.0f*s2 + 2.0f*s3 + s4);

    float u1 = A2 - K2 * vc2;
    float u2 = A2 - K2 * fmaf(0.5f, u1, vc2);
    float u3 = A2 - K2 * fmaf(0.5f, u2, vc2);
    float u4 = A2 - K2 * (vc2 + u3);
    vc2 = vc2 + (1.0f/6.0f) * (u1 + 2.0f*u2 + 2.0f*u3 + u4);

    soc = soc - ik * (1.0f/10800.0f);     // DT/Q_AS, DT=1
    soc = fminf(fmaxf(soc, 0.0f), 1.0f);
  }
}

extern "C" void kernel_launch(void* const* d_in, const int* in_sizes, int n_in,
                              void* d_out, int out_size, void* d_ws, size_t ws_size,
                              hipStream_t stream)
{
  // setup_inputs order: V, I, Tz, soc0, W1, b1, W2, b2, Wr1, br1, Wr2, br2
  const float* gI   = (const float*)d_in[1];
  const float* gT   = (const float*)d_in[2];
  const float* gs0  = (const float*)d_in[3];
  const float* gW1  = (const float*)d_in[4];
  const float* gb1  = (const float*)d_in[5];
  const float* gW2  = (const float*)d_in[6];
  const float* gb2  = (const float*)d_in[7];
  const float* gWr1 = (const float*)d_in[8];
  const float* gbr1 = (const float*)d_in[9];
  const float* gWr2 = (const float*)d_in[10];
  const float* gbr2 = (const float*)d_in[11];

  float* gV = (float*)d_out;                                  // (B,H)
  float* gP = gV + (size_t)B_TOT * H_STEPS;                   // (B,H,5)
  float* gS = gP + (size_t)B_TOT * H_STEPS * 5;               // (B,H,3)

  dim3 grid((B_TOT * 4) / 256);   // 4 lanes per battery
  dim3 block(256);
  hipLaunchKernelGGL(dcir_node_kernel, grid, block, 0, stream,
                     gI, gT, gs0, gW1, gb1, gW2, gb2, gWr1, gbr1, gWr2, gbr2,
                     gV, gP, gS);
}

// Round 2
// 2449.840 us; speedup vs baseline: 1.1333x; 1.1333x over previous
//
#include <hip/hip_runtime.h>
#include <cstddef>

#define B_TOT 32768
#define H_STEPS 256
#define HIDN 128
#define RHIDN 64
#define CHUNK 16

// per-wave LDS staging region layout (float element offsets).
// Padded per-battery strides (20/84/52: stride%32 = 20 -> 8 banks, 2-way max)
// and 16B-aligned rows so writeback can use ds_read_b128.
#define OFF_V 0       // 16 batteries * 20   (16 steps V, pad 4)
#define OFF_P 320     // 16 * 84             (16*5 P, pad 4)
#define OFF_S 1664    // 16 * 52             (16*3 S, pad 4)
#define OFF_I 2496    // 16 * 20
#define OFF_T 2816    // 16 * 20
#define OFF_D 3136    // 64 dump words (unused-slot sink)
#define WREG  3200    // floats per wave = 12.8KB; x4 waves = 51.2KB

__device__ __forceinline__ float frcp(float x){ return __builtin_amdgcn_rcpf(x); }

__device__ __forceinline__ float fast_tanh(float x){
  float e = __expf(x + x);
  return 1.0f - 2.0f * frcp(e + 1.0f);
}

__device__ __forceinline__ float fast_softplus(float x){
  float e = __expf(-fabsf(x));
  return fmaxf(x, 0.0f) + __logf(1.0f + e);
}

__global__ __launch_bounds__(256, 2)
void dcir_node_kernel(const float* __restrict__ gI,
                      const float* __restrict__ gT,
                      const float* __restrict__ gsoc0,
                      const float* __restrict__ gW1,
                      const float* __restrict__ gb1,
                      const float* __restrict__ gW2,
                      const float* __restrict__ gb2,
                      const float* __restrict__ gWr1,
                      const float* __restrict__ gbr1,
                      const float* __restrict__ gWr2,
                      const float* __restrict__ gbr2,
                      float* __restrict__ gV,
                      float* __restrict__ gP,
                      float* __restrict__ gS)
{
  __shared__ float4 hw[32][4][2];   // param-head weights, quad-interleaved
  __shared__ float4 rw[16][4][2];   // residual weights, quad-interleaved
  __shared__ __attribute__((aligned(16))) float wsbuf[4][WREG];

  const int tid = threadIdx.x;
  if (tid < HIDN){
    int j = tid;
    hw[j & 31][j >> 5][0] = make_float4(gW1[j], gW1[HIDN + j], gb1[j], gW2[j*5 + 0]);
    hw[j & 31][j >> 5][1] = make_float4(gW2[j*5+1], gW2[j*5+2], gW2[j*5+3], gW2[j*5+4]);
  } else if (tid < HIDN + RHIDN){
    int u = tid - HIDN;
    rw[u & 15][u >> 4][0] = make_float4(gWr1[0*RHIDN+u], gWr1[1*RHIDN+u],
                                        gWr1[2*RHIDN+u], gWr1[3*RHIDN+u]);
    rw[u & 15][u >> 4][1] = make_float4(gWr1[4*RHIDN+u], gbr1[u], gWr2[u], 0.0f);
  }
  __syncthreads();

  const int w    = tid >> 6;
  const int lane = tid & 63;
  const int bb   = lane >> 2;   // battery within wave (0..15)
  const int q    = lane & 3;    // quad position
  float* __restrict__ ws = wsbuf[w];

  const int gtid = blockIdx.x * 256 + tid;
  const int b = gtid >> 2;      // global battery

  const float b20 = gb2[0], b21 = gb2[1], b22 = gb2[2], b23 = gb2[3], b24 = gb2[4];
  const float br2v = gbr2[0];

  float soc = gsoc0[b];
  float vc1 = 0.0f, vc2 = 0.0f;

  const float* __restrict__ Ib = gI + (size_t)b * H_STEPS;
  const float* __restrict__ Tb = gT + (size_t)b * H_STEPS;
  float* __restrict__ Vb = gV + (size_t)b * H_STEPS;
  float* __restrict__ Pb = gP + (size_t)b * H_STEPS * 5;
  float* __restrict__ Sb = gS + (size_t)b * H_STEPS * 3;

  // Per-lane LDS staging slots: 3 scalar writes/step, address = base + kk*stride.
  int baseA, strA, baseB, strB, baseC, strC;
  if (q == 0){      baseA = OFF_V + bb*20;     strA = 1;
                    baseB = OFF_S + bb*52;     strB = 3;
                    baseC = OFF_D + lane;      strC = 0; }
  else if (q == 1){ baseA = OFF_P + bb*84 + 0; strA = 5;
                    baseB = OFF_P + bb*84 + 1; strB = 5;
                    baseC = OFF_S + bb*52 + 1; strC = 3; }
  else if (q == 2){ baseA = OFF_P + bb*84 + 2; strA = 5;
                    baseB = OFF_P + bb*84 + 3; strB = 5;
                    baseC = OFF_S + bb*52 + 2; strC = 3; }
  else {            baseA = OFF_P + bb*84 + 4; strA = 5;
                    baseB = OFF_D + lane;      strB = 0;
                    baseC = OFF_D + lane;      strC = 0; }

  for (int c0 = 0; c0 < H_STEPS; c0 += CHUNK){
    // ---- stage input chunk (coalesced float4: quad covers 64B per battery)
    float4 iv = *(const float4*)(Ib + c0 + q*4);
    float4 tv = *(const float4*)(Tb + c0 + q*4);
    *(float4*)&ws[OFF_I + bb*20 + q*4] = iv;
    *(float4*)&ws[OFF_T + bb*20 + q*4] = tv;
    __builtin_amdgcn_wave_barrier();   // wave-private LDS: HW processes per-wave ds ops in order

    #pragma unroll 1
    for (int kk = 0; kk < CHUNK; ++kk){
      const float ik = ws[OFF_I + bb*20 + kk];   // broadcast ds_read
      const float tk = ws[OFF_T + bb*20 + kk];

      // ---- param head: h = tanh([soc,t]@W1 + b1); logits = h@W2
      float a0=0.f, a1=0.f, a2=0.f, a3=0.f, a4=0.f;
      #pragma unroll
      for (int it = 0; it < 32; ++it){
        const float4 wa = hw[it][q][0];
        const float4 wb = hw[it][q][1];
        float arg = fmaf(soc, wa.x, fmaf(tk, wa.y, wa.z));
        float h = fast_tanh(arg);
        a0 = fmaf(h, wa.w, a0);
        a1 = fmaf(h, wb.x, a1);
        a2 = fmaf(h, wb.y, a2);
        a3 = fmaf(h, wb.z, a3);
        a4 = fmaf(h, wb.w, a4);
      }
      a0 += __shfl_xor(a0, 1, 4); a0 += __shfl_xor(a0, 2, 4);
      a1 += __shfl_xor(a1, 1, 4); a1 += __shfl_xor(a1, 2, 4);
      a2 += __shfl_xor(a2, 1, 4); a2 += __shfl_xor(a2, 2, 4);
      a3 += __shfl_xor(a3, 1, 4); a3 += __shfl_xor(a3, 2, 4);
      a4 += __shfl_xor(a4, 1, 4); a4 += __shfl_xor(a4, 2, 4);

      const float R0 = fmaf(fast_softplus(a0 + b20), 0.005f,   1e-6f);
      const float R1 = fmaf(fast_softplus(a1 + b21), 0.005f,   1e-6f);
      const float C1 = fmaf(fast_softplus(a2 + b22), 2000.0f,  1e-6f);
      const float R2 = fmaf(fast_softplus(a3 + b23), 0.005f,   1e-6f);
      const float C2 = fmaf(fast_softplus(a4 + b24), 10000.0f, 1e-6f);

      // ---- residual MLP on [vc1,vc2,soc,i,t]
      float ra = 0.0f;
      #pragma unroll
      for (int it = 0; it < 16; ++it){
        const float4 wa = rw[it][q][0];
        const float4 wb = rw[it][q][1];
        float arg = fmaf(vc1, wa.x,
                    fmaf(vc2, wa.y,
                    fmaf(soc, wa.z,
                    fmaf(ik,  wa.w,
                    fmaf(tk,  wb.x, wb.y)))));
        ra = fmaf(fast_tanh(arg), wb.z, ra);
      }
      ra += __shfl_xor(ra, 1, 4); ra += __shfl_xor(ra, 2, 4);

      const float res = (ra + br2v) * 0.01f;
      const float ocv = fmaf(1.2f, soc, 3.0f) - 0.4f * __expf(-12.0f * soc);
      const float Vp  = ocv - R0 * ik - vc1 - vc2 + res;

      // ---- stage outputs for step k (pre-update state) into wave-private LDS
      float vA = q==0 ? Vp  : (q==1 ? R0 : (q==2 ? C1 : C2));
      float vB = q==0 ? vc1 : (q==1 ? R1 : R2);
      float vC = q==1 ? vc2 : soc;
      ws[baseA + kk*strA] = vA;
      ws[baseB + kk*strB] = vB;
      ws[baseC + kk*strC] = vC;

      // ---- RK4 on the affine ODE
      const float A1 = ik * frcp(C1);
      const float A2 = ik * frcp(C2);
      const float K1 = frcp(R1 * C1);
      const float K2 = frcp(R2 * C2);

      float s1 = A1 - K1 * vc1;
      float s2 = A1 - K1 * fmaf(0.5f, s1, vc1);
      float s3 = A1 - K1 * fmaf(0.5f, s2, vc1);
      float s4 = A1 - K1 * (vc1 + s3);
      vc1 = vc1 + (1.0f/6.0f) * (s1 + 2.0f*s2 + 2.0f*s3 + s4);

      float u1 = A2 - K2 * vc2;
      float u2 = A2 - K2 * fmaf(0.5f, u1, vc2);
      float u3 = A2 - K2 * fmaf(0.5f, u2, vc2);
      float u4 = A2 - K2 * (vc2 + u3);
      vc2 = vc2 + (1.0f/6.0f) * (u1 + 2.0f*u2 + 2.0f*u3 + u4);

      soc = soc - ik * (1.0f/10800.0f);
      soc = fminf(fmaxf(soc, 0.0f), 1.0f);
    }
    __builtin_amdgcn_wave_barrier();

    // ---- coalesced writeback: each quad covers contiguous 64B segments
    {
      float4 v4 = *(float4*)&ws[OFF_V + bb*20 + q*4];
      *(float4*)(Vb + c0 + q*4) = v4;
      #pragma unroll
      for (int j5 = 0; j5 < 5; ++j5){
        int j = q + j5*4;
        float4 p4 = *(float4*)&ws[OFF_P + bb*84 + j*4];
        *(float4*)(Pb + (size_t)c0*5 + j*4) = p4;
      }
      #pragma unroll
      for (int j3 = 0; j3 < 3; ++j3){
        int j = q + j3*4;
        float4 s4 = *(float4*)&ws[OFF_S + bb*52 + j*4];
        *(float4*)(Sb + (size_t)c0*3 + j*4) = s4;
      }
    }
    __builtin_amdgcn_wave_barrier();
  }
}

extern "C" void kernel_launch(void* const* d_in, const int* in_sizes, int n_in,
                              void* d_out, int out_size, void* d_ws, size_t ws_size,
                              hipStream_t stream)
{
  // setup_inputs order: V, I, Tz, soc0, W1, b1, W2, b2, Wr1, br1, Wr2, br2
  const float* gI   = (const float*)d_in[1];
  const float* gT   = (const float*)d_in[2];
  const float* gs0  = (const float*)d_in[3];
  const float* gW1  = (const float*)d_in[4];
  const float* gb1  = (const float*)d_in[5];
  const float* gW2  = (const float*)d_in[6];
  const float* gb2  = (const float*)d_in[7];
  const float* gWr1 = (const float*)d_in[8];
  const float* gbr1 = (const float*)d_in[9];
  const float* gWr2 = (const float*)d_in[10];
  const float* gbr2 = (const float*)d_in[11];

  float* gV = (float*)d_out;                                  // (B,H)
  float* gP = gV + (size_t)B_TOT * H_STEPS;                   // (B,H,5)
  float* gS = gP + (size_t)B_TOT * H_STEPS * 5;               // (B,H,3)

  dim3 grid((B_TOT * 4) / 256);   // 4 lanes per battery
  dim3 block(256);
  hipLaunchKernelGGL(dcir_node_kernel, grid, block, 0, stream,
                     gI, gT, gs0, gW1, gb1, gW2, gb2, gWr1, gbr1, gWr2, gbr2,
                     gV, gP, gS);
}

// Round 4
// 1114.273 us; speedup vs baseline: 2.4918x; 2.1986x over previous
//
#include <hip/hip_runtime.h>
#include <cstddef>

#define B_TOT 32768
#define H_STEPS 256
#define HIDN 128
#define RHIDN 64
#define CHUNK 16

// Per-wave LDS staging layout (float element offsets). 32 batteries per wave
// (2 per quad). Per-battery strides padded (20/84/52) to break pow2 bank
// patterns; all offsets 16B-aligned for ds_read_b128/ds_write_b128.
#define OFF_V 0        // 32 * 20
#define OFF_P 640      // 32 * 84
#define OFF_S 3328     // 32 * 52
#define OFF_I 4992     // 32 * 20
#define OFF_T 5632     // 32 * 20
#define OFF_D 6272     // 64 dump words (sink for unused role slots)
#define WREG  6336     // floats per wave = 25344B; x4 waves = 101376B

typedef float vf4 __attribute__((ext_vector_type(4)));

__device__ __forceinline__ float frcp(float x){ return __builtin_amdgcn_rcpf(x); }

__device__ __forceinline__ float fast_tanh(float x){
  float e = __expf(x + x);
  return 1.0f - 2.0f * frcp(e + 1.0f);
}

__device__ __forceinline__ float fast_softplus(float x){
  float e = __expf(-fabsf(x));
  return fmaxf(x, 0.0f) + __logf(1.0f + e);
}

__device__ __forceinline__ vf4 nt_load4(const float* p){
  return __builtin_nontemporal_load((const vf4*)p);
}
__device__ __forceinline__ void nt_store4(float* p, vf4 v){
  __builtin_nontemporal_store(v, (vf4*)p);
}

__global__ __launch_bounds__(256, 1)
void dcir_node_kernel(const float* __restrict__ gI,
                      const float* __restrict__ gT,
                      const float* __restrict__ gsoc0,
                      const float* __restrict__ gW1,
                      const float* __restrict__ gb1,
                      const float* __restrict__ gW2,
                      const float* __restrict__ gb2,
                      const float* __restrict__ gWr1,
                      const float* __restrict__ gbr1,
                      const float* __restrict__ gWr2,
                      const float* __restrict__ gbr2,
                      float* __restrict__ gV,
                      float* __restrict__ gP,
                      float* __restrict__ gS)
{
  __shared__ float4 hw[32][4][2];   // param-head weights, quad-interleaved
  __shared__ float4 rw[16][4][2];   // residual weights, quad-interleaved
  __shared__ __attribute__((aligned(16))) float wsbuf[4][WREG];

  const int tid = threadIdx.x;
  if (tid < HIDN){
    int j = tid;
    hw[j & 31][j >> 5][0] = make_float4(gW1[j], gW1[HIDN + j], gb1[j], gW2[j*5 + 0]);
    hw[j & 31][j >> 5][1] = make_float4(gW2[j*5+1], gW2[j*5+2], gW2[j*5+3], gW2[j*5+4]);
  } else if (tid < HIDN + RHIDN){
    int u = tid - HIDN;
    rw[u & 15][u >> 4][0] = make_float4(gWr1[0*RHIDN+u], gWr1[1*RHIDN+u],
                                        gWr1[2*RHIDN+u], gWr1[3*RHIDN+u]);
    rw[u & 15][u >> 4][1] = make_float4(gWr1[4*RHIDN+u], gbr1[u], gWr2[u], 0.0f);
  }
  __syncthreads();

  const int w    = tid >> 6;
  const int lane = tid & 63;
  const int qd   = lane >> 2;          // quad index (0..15)
  const int q    = lane & 3;           // lane within quad
  float* __restrict__ ws = wsbuf[w];

  const int wbase = (blockIdx.x * 4 + w) * 32;  // wave's first battery
  const int bw0 = 2*qd, bw1 = 2*qd + 1;         // this quad's two batteries (in-wave)
  const int b0 = wbase + bw0, b1 = wbase + bw1; // global battery ids

  const float b20 = gb2[0], b21 = gb2[1], b22 = gb2[2], b23 = gb2[3], b24 = gb2[4];
  const float br2v = gbr2[0];

  float soc[2], vc1[2], vc2[2];
  soc[0] = gsoc0[b0]; soc[1] = gsoc0[b1];
  vc1[0] = vc1[1] = 0.0f; vc2[0] = vc2[1] = 0.0f;

  // Per-(q,battery) staging slots: 3 scalar writes/step each.
  int baseA[2], baseB[2], baseC[2];
  int strA, strB, strC;
  #pragma unroll
  for (int j = 0; j < 2; ++j){
    const int bw = 2*qd + j;
    if (q == 0){      baseA[j] = OFF_V + bw*20;
                      baseB[j] = OFF_S + bw*52;
                      baseC[j] = OFF_D + lane; }
    else if (q == 1){ baseA[j] = OFF_P + bw*84 + 0;
                      baseB[j] = OFF_P + bw*84 + 1;
                      baseC[j] = OFF_S + bw*52 + 1; }
    else if (q == 2){ baseA[j] = OFF_P + bw*84 + 2;
                      baseB[j] = OFF_P + bw*84 + 3;
                      baseC[j] = OFF_S + bw*52 + 2; }
    else {            baseA[j] = OFF_P + bw*84 + 4;
                      baseB[j] = OFF_D + lane;
                      baseC[j] = OFF_D + lane; }
  }
  strA = (q == 0) ? 1 : 5;
  strB = (q == 0) ? 3 : ((q == 3) ? 0 : 5);
  strC = (q == 1 || q == 2) ? 3 : 0;

  for (int c0 = 0; c0 < H_STEPS; c0 += CHUNK){
    // ---- stage input chunk: 128 float4 segments per array per wave
    #pragma unroll
    for (int r = 0; r < 2; ++r){
      int s = lane + r*64;
      int bw = s >> 2, sub = s & 3;
      int gb = wbase + bw;
      vf4 iv = nt_load4(gI + (size_t)gb*H_STEPS + c0 + sub*4);
      vf4 tv = nt_load4(gT + (size_t)gb*H_STEPS + c0 + sub*4);
      *(vf4*)&ws[OFF_I + bw*20 + sub*4] = iv;
      *(vf4*)&ws[OFF_T + bw*20 + sub*4] = tv;
    }
    __builtin_amdgcn_wave_barrier();

    #pragma unroll 1
    for (int kk = 0; kk < CHUNK; ++kk){
      float ik[2], tk[2];
      ik[0] = ws[OFF_I + bw0*20 + kk];  ik[1] = ws[OFF_I + bw1*20 + kk];
      tk[0] = ws[OFF_T + bw0*20 + kk];  tk[1] = ws[OFF_T + bw1*20 + kk];

      // ---- param head (both batteries share each weight read)
      float a0[2]={0,0}, a1[2]={0,0}, a2[2]={0,0}, a3[2]={0,0}, a4[2]={0,0};
      #pragma unroll
      for (int it = 0; it < 32; ++it){
        const float4 wa = hw[it][q][0];
        const float4 wb = hw[it][q][1];
        #pragma unroll
        for (int j = 0; j < 2; ++j){
          float arg = fmaf(soc[j], wa.x, fmaf(tk[j], wa.y, wa.z));
          float h = fast_tanh(arg);
          a0[j] = fmaf(h, wa.w, a0[j]);
          a1[j] = fmaf(h, wb.x, a1[j]);
          a2[j] = fmaf(h, wb.y, a2[j]);
          a3[j] = fmaf(h, wb.z, a3[j]);
          a4[j] = fmaf(h, wb.w, a4[j]);
        }
      }
      #pragma unroll
      for (int j = 0; j < 2; ++j){
        a0[j] += __shfl_xor(a0[j], 1, 4); a0[j] += __shfl_xor(a0[j], 2, 4);
        a1[j] += __shfl_xor(a1[j], 1, 4); a1[j] += __shfl_xor(a1[j], 2, 4);
        a2[j] += __shfl_xor(a2[j], 1, 4); a2[j] += __shfl_xor(a2[j], 2, 4);
        a3[j] += __shfl_xor(a3[j], 1, 4); a3[j] += __shfl_xor(a3[j], 2, 4);
        a4[j] += __shfl_xor(a4[j], 1, 4); a4[j] += __shfl_xor(a4[j], 2, 4);
      }

      float R0[2], R1[2], C1[2], R2[2], C2[2];
      #pragma unroll
      for (int j = 0; j < 2; ++j){
        R0[j] = fmaf(fast_softplus(a0[j] + b20), 0.005f,   1e-6f);
        R1[j] = fmaf(fast_softplus(a1[j] + b21), 0.005f,   1e-6f);
        C1[j] = fmaf(fast_softplus(a2[j] + b22), 2000.0f,  1e-6f);
        R2[j] = fmaf(fast_softplus(a3[j] + b23), 0.005f,   1e-6f);
        C2[j] = fmaf(fast_softplus(a4[j] + b24), 10000.0f, 1e-6f);
      }

      // ---- residual MLP
      float ra[2] = {0.0f, 0.0f};
      #pragma unroll
      for (int it = 0; it < 16; ++it){
        const float4 wa = rw[it][q][0];
        const float4 wb = rw[it][q][1];
        #pragma unroll
        for (int j = 0; j < 2; ++j){
          float arg = fmaf(vc1[j], wa.x,
                      fmaf(vc2[j], wa.y,
                      fmaf(soc[j], wa.z,
                      fmaf(ik[j],  wa.w,
                      fmaf(tk[j],  wb.x, wb.y)))));
          ra[j] = fmaf(fast_tanh(arg), wb.z, ra[j]);
        }
      }
      #pragma unroll
      for (int j = 0; j < 2; ++j){
        ra[j] += __shfl_xor(ra[j], 1, 4); ra[j] += __shfl_xor(ra[j], 2, 4);
      }

      #pragma unroll
      for (int j = 0; j < 2; ++j){
        const float res = (ra[j] + br2v) * 0.01f;
        const float ocv = fmaf(1.2f, soc[j], 3.0f) - 0.4f * __expf(-12.0f * soc[j]);
        const float Vp  = ocv - R0[j] * ik[j] - vc1[j] - vc2[j] + res;

        // stage outputs for step k (pre-update state)
        float vA = q==0 ? Vp     : (q==1 ? R0[j] : (q==2 ? C1[j] : C2[j]));
        float vB = q==0 ? vc1[j] : (q==1 ? R1[j] : R2[j]);
        float vC = q==1 ? vc2[j] : soc[j];
        ws[baseA[j] + kk*strA] = vA;
        ws[baseB[j] + kk*strB] = vB;
        ws[baseC[j] + kk*strC] = vC;

        // RK4 on the affine ODE
        const float A1 = ik[j] * frcp(C1[j]);
        const float A2 = ik[j] * frcp(C2[j]);
        const float K1 = frcp(R1[j] * C1[j]);
        const float K2 = frcp(R2[j] * C2[j]);

        float s1 = A1 - K1 * vc1[j];
        float s2 = A1 - K1 * fmaf(0.5f, s1, vc1[j]);
        float s3 = A1 - K1 * fmaf(0.5f, s2, vc1[j]);
        float s4 = A1 - K1 * (vc1[j] + s3);
        vc1[j] = vc1[j] + (1.0f/6.0f) * (s1 + 2.0f*s2 + 2.0f*s3 + s4);

        float u1 = A2 - K2 * vc2[j];
        float u2 = A2 - K2 * fmaf(0.5f, u1, vc2[j]);
        float u3 = A2 - K2 * fmaf(0.5f, u2, vc2[j]);
        float u4 = A2 - K2 * (vc2[j] + u3);
        vc2[j] = vc2[j] + (1.0f/6.0f) * (u1 + 2.0f*u2 + 2.0f*u3 + u4);

        soc[j] = soc[j] - ik[j] * (1.0f/10800.0f);
        soc[j] = fminf(fmaxf(soc[j], 0.0f), 1.0f);
      }
    }
    __builtin_amdgcn_wave_barrier();

    // ---- writeback (non-temporal, full-line contiguous runs per battery)
    // V: 128 float4 segments (32 bat x 4)
    #pragma unroll
    for (int r = 0; r < 2; ++r){
      int s = lane + r*64;
      int bw = s >> 2, sub = s & 3;
      vf4 v = *(vf4*)&ws[OFF_V + bw*20 + sub*4];
      nt_store4(gV + (size_t)(wbase + bw)*H_STEPS + c0 + sub*4, v);
    }
    // P: 640 float4 segments (32 bat x 20)
    #pragma unroll
    for (int r = 0; r < 10; ++r){
      int s = lane + r*64;
      int bw = s / 20, sub = s % 20;
      vf4 v = *(vf4*)&ws[OFF_P + bw*84 + sub*4];
      nt_store4(gP + (size_t)(wbase + bw)*H_STEPS*5 + (size_t)c0*5 + sub*4, v);
    }
    // S: 384 float4 segments (32 bat x 12)
    #pragma unroll
    for (int r = 0; r < 6; ++r){
      int s = lane + r*64;
      int bw = s / 12, sub = s % 12;
      vf4 v = *(vf4*)&ws[OFF_S + bw*52 + sub*4];
      nt_store4(gS + (size_t)(wbase + bw)*H_STEPS*3 + (size_t)c0*3 + sub*4, v);
    }
    __builtin_amdgcn_wave_barrier();
  }
}

extern "C" void kernel_launch(void* const* d_in, const int* in_sizes, int n_in,
                              void* d_out, int out_size, void* d_ws, size_t ws_size,
                              hipStream_t stream)
{
  // setup_inputs order: V, I, Tz, soc0, W1, b1, W2, b2, Wr1, br1, Wr2, br2
  const float* gI   = (const float*)d_in[1];
  const float* gT   = (const float*)d_in[2];
  const float* gs0  = (const float*)d_in[3];
  const float* gW1  = (const float*)d_in[4];
  const float* gb1  = (const float*)d_in[5];
  const float* gW2  = (const float*)d_in[6];
  const float* gb2  = (const float*)d_in[7];
  const float* gWr1 = (const float*)d_in[8];
  const float* gbr1 = (const float*)d_in[9];
  const float* gWr2 = (const float*)d_in[10];
  const float* gbr2 = (const float*)d_in[11];

  float* gV = (float*)d_out;                                  // (B,H)
  float* gP = gV + (size_t)B_TOT * H_STEPS;                   // (B,H,5)
  float* gS = gP + (size_t)B_TOT * H_STEPS * 5;               // (B,H,3)

  // 2 batteries per quad -> B*4/2 threads
  dim3 grid((B_TOT * 4 / 2) / 256);   // 256 blocks, 1 per CU (LDS-bound)
  dim3 block(256);
  hipLaunchKernelGGL(dcir_node_kernel, grid, block, 0, stream,
                     gI, gT, gs0, gW1, gb1, gW2, gb2, gWr1, gbr1, gWr2, gbr2,
                     gV, gP, gS);
}

// Round 5
// 940.692 us; speedup vs baseline: 2.9516x; 1.1845x over previous
//
#include <hip/hip_runtime.h>
#include <cstddef>

#define B_TOT 32768
#define H_STEPS 256
#define HIDN 128
#define RHIDN 64
#define CHUNK 16

// Per-wave LDS staging layout (float element offsets). 16 batteries per wave
// (2 per octet, 8 role-lanes per battery-pair). Strides 20/84/52 break pow2
// bank patterns; all rows 16B-aligned for float4 writeback reads.
#define OFF_V 0        // 16 * 20
#define OFF_P 320      // 16 * 84
#define OFF_S 1664     // 16 * 52
#define OFF_I 2496     // 16 * 20
#define OFF_T 2816     // 16 * 20
#define OFF_D 3136     // 64 dump words
#define WREG  3200     // floats per wave = 12.8KB; x4 waves = 51.2KB

#define C2L   2.8853900817779268f   // 2*log2(e)  (tanh prescale)
#define L2E   1.4426950408889634f   // log2(e)
#define LN2   0.6931471805599453f

typedef float vf4 __attribute__((ext_vector_type(4)));

__device__ __forceinline__ float frcp(float x){ return __builtin_amdgcn_rcpf(x); }
__device__ __forceinline__ float fexp2(float x){ return __builtin_amdgcn_exp2f(x); }
__device__ __forceinline__ float flog2(float x){ return __builtin_amdgcn_logf(x); }

// softplus(x) = max(x,0) + ln2 * log2(1 + exp2(-|x|*log2e))
__device__ __forceinline__ float fast_softplus(float x){
  float e = fexp2(-fabsf(x) * L2E);
  return fmaxf(x, 0.0f) + LN2 * flog2(1.0f + e);
}

__device__ __forceinline__ vf4 nt_load4(const float* p){
  return __builtin_nontemporal_load((const vf4*)p);
}
__device__ __forceinline__ void nt_store4(float* p, vf4 v){
  __builtin_nontemporal_store(v, (vf4*)p);
}

__global__ __launch_bounds__(256, 2)
void dcir_node_kernel(const float* __restrict__ gI,
                      const float* __restrict__ gT,
                      const float* __restrict__ gsoc0,
                      const float* __restrict__ gW1,
                      const float* __restrict__ gb1,
                      const float* __restrict__ gW2,
                      const float* __restrict__ gb2,
                      const float* __restrict__ gWr1,
                      const float* __restrict__ gbr1,
                      const float* __restrict__ gWr2,
                      const float* __restrict__ gbr2,
                      float* __restrict__ gV,
                      float* __restrict__ gP,
                      float* __restrict__ gS)
{
  // Weight tables, role-interleaved: for fixed (it,k) the 8 role lanes read
  // 8 contiguous 16B slots = 128B = all 32 banks once (conflict-free bcast).
  __shared__ float4 hw[16][2][8];   // unit j = o*16+it (prescaled W1,b1; raw W2)
  __shared__ float4 rw[8][2][8];    // unit u = o*8+it  (prescaled Wr1,br1; raw Wr2)
  __shared__ float  csum[8];        // [0..4]=colsum(W2), [5]=sum(Wr2)
  __shared__ __attribute__((aligned(16))) float wsbuf[4][WREG];

  const int tid = threadIdx.x;
  if (tid < HIDN){
    int j = tid, it = j & 15, o = j >> 4;
    hw[it][0][o] = make_float4(gW1[j]*C2L, gW1[HIDN + j]*C2L, gb1[j]*C2L, gW2[j*5 + 0]);
    hw[it][1][o] = make_float4(gW2[j*5+1], gW2[j*5+2], gW2[j*5+3], gW2[j*5+4]);
  } else if (tid < HIDN + RHIDN){
    int u = tid - HIDN, it = u & 7, o = u >> 3;
    rw[it][0][o] = make_float4(gWr1[0*RHIDN+u]*C2L, gWr1[1*RHIDN+u]*C2L,
                               gWr1[2*RHIDN+u]*C2L, gWr1[3*RHIDN+u]*C2L);
    rw[it][1][o] = make_float4(gWr1[4*RHIDN+u]*C2L, gbr1[u]*C2L, gWr2[u], 0.0f);
  } else if (tid < HIDN + RHIDN + 5){
    int m = tid - HIDN - RHIDN;
    float s = 0.0f;
    for (int j = 0; j < HIDN; ++j) s += gW2[j*5 + m];
    csum[m] = s;
  } else if (tid == HIDN + RHIDN + 5){
    float s = 0.0f;
    for (int u = 0; u < RHIDN; ++u) s += gWr2[u];
    csum[5] = s;
  }
  __syncthreads();

  const int w    = tid >> 6;
  const int lane = tid & 63;
  const int oct  = lane >> 3;          // octet index (0..7)
  const int o    = lane & 7;           // role lane within octet
  float* __restrict__ ws = wsbuf[w];

  const int wbase = (blockIdx.x * 4 + w) * 16;   // wave's first battery
  const int bw0 = 2*oct, bw1 = 2*oct + 1;
  const int b0 = wbase + bw0, b1g = wbase + bw1;

  // colsum + b2 folded: a_m = cb_m - 2*acc_m, with cb = colsum + b2
  const float cb0 = csum[0] + gb2[0], cb1 = csum[1] + gb2[1],
              cb2v = csum[2] + gb2[2], cb3 = csum[3] + gb2[3],
              cb4 = csum[4] + gb2[4];
  const float rb = csum[5] + gbr2[0];  // ra_true + br2 = rb - 2*racc

  float soc[2], vc1[2], vc2[2];
  soc[0] = gsoc0[b0]; soc[1] = gsoc0[b1g];
  vc1[0] = vc1[1] = 0.0f; vc2[0] = vc2[1] = 0.0f;

  // Per-(role,battery) staging slots.
  int baseA[2], baseB[2];
  #pragma unroll
  for (int j = 0; j < 2; ++j){
    const int bw = 2*oct + j;
    baseA[j] = (o == 0) ? OFF_V + bw*20
             : (o <= 5) ? OFF_P + bw*84 + (o-1)
                        : OFF_S + bw*52 + (o-6);
    baseB[j] = (o == 0) ? OFF_S + bw*52 + 2 : OFF_D + lane;
  }
  const int strA = (o == 0) ? 1 : ((o <= 5) ? 5 : 3);
  const int strB = (o == 0) ? 3 : 0;

  for (int c0 = 0; c0 < H_STEPS; c0 += CHUNK){
    // ---- stage input chunk: 64 float4 per array per wave (1 per lane)
    {
      int bw = lane >> 2, sub = lane & 3;
      int gb = wbase + bw;
      vf4 iv = nt_load4(gI + (size_t)gb*H_STEPS + c0 + sub*4);
      vf4 tv = nt_load4(gT + (size_t)gb*H_STEPS + c0 + sub*4);
      *(vf4*)&ws[OFF_I + bw*20 + sub*4] = iv;
      *(vf4*)&ws[OFF_T + bw*20 + sub*4] = tv;
    }
    __builtin_amdgcn_wave_barrier();

    #pragma unroll 1
    for (int kk = 0; kk < CHUNK; ++kk){
      float ik[2], tk[2];
      ik[0] = ws[OFF_I + bw0*20 + kk];  ik[1] = ws[OFF_I + bw1*20 + kk];
      tk[0] = ws[OFF_T + bw0*20 + kk];  tk[1] = ws[OFF_T + bw1*20 + kk];

      // ---- param head: r = rcp(exp2(arg')+1) with arg' prescaled by 2*log2e;
      //      tanh folded: a_m = cb_m - 2 * sum(r * W2[:,m])
      float a0[2]={0,0}, a1[2]={0,0}, a2[2]={0,0}, a3[2]={0,0}, a4[2]={0,0};
      #pragma unroll
      for (int it = 0; it < 16; ++it){
        const float4 wa = hw[it][0][o];
        const float4 wb = hw[it][1][o];
        #pragma unroll
        for (int j = 0; j < 2; ++j){
          float arg = fmaf(soc[j], wa.x, fmaf(tk[j], wa.y, wa.z));
          float r = frcp(fexp2(arg) + 1.0f);
          a0[j] = fmaf(r, wa.w, a0[j]);
          a1[j] = fmaf(r, wb.x, a1[j]);
          a2[j] = fmaf(r, wb.y, a2[j]);
          a3[j] = fmaf(r, wb.z, a3[j]);
          a4[j] = fmaf(r, wb.w, a4[j]);
        }
      }
      #pragma unroll
      for (int j = 0; j < 2; ++j){
        a0[j] += __shfl_xor(a0[j], 1, 8); a0[j] += __shfl_xor(a0[j], 2, 8); a0[j] += __shfl_xor(a0[j], 4, 8);
        a1[j] += __shfl_xor(a1[j], 1, 8); a1[j] += __shfl_xor(a1[j], 2, 8); a1[j] += __shfl_xor(a1[j], 4, 8);
        a2[j] += __shfl_xor(a2[j], 1, 8); a2[j] += __shfl_xor(a2[j], 2, 8); a2[j] += __shfl_xor(a2[j], 4, 8);
        a3[j] += __shfl_xor(a3[j], 1, 8); a3[j] += __shfl_xor(a3[j], 2, 8); a3[j] += __shfl_xor(a3[j], 4, 8);
        a4[j] += __shfl_xor(a4[j], 1, 8); a4[j] += __shfl_xor(a4[j], 2, 8); a4[j] += __shfl_xor(a4[j], 4, 8);
      }

      float R0[2], R1[2], C1[2], R2[2], C2[2];
      #pragma unroll
      for (int j = 0; j < 2; ++j){
        R0[j] = fmaf(fast_softplus(fmaf(-2.0f, a0[j], cb0)),  0.005f,   1e-6f);
        R1[j] = fmaf(fast_softplus(fmaf(-2.0f, a1[j], cb1)),  0.005f,   1e-6f);
        C1[j] = fmaf(fast_softplus(fmaf(-2.0f, a2[j], cb2v)), 2000.0f,  1e-6f);
        R2[j] = fmaf(fast_softplus(fmaf(-2.0f, a3[j], cb3)),  0.005f,   1e-6f);
        C2[j] = fmaf(fast_softplus(fmaf(-2.0f, a4[j], cb4)),  10000.0f, 1e-6f);
      }

      // ---- residual MLP (prescaled weights; tanh folded into rsum - 2*racc)
      float ra[2] = {0.0f, 0.0f};
      #pragma unroll
      for (int it = 0; it < 8; ++it){
        const float4 wa = rw[it][0][o];
        const float4 wb = rw[it][1][o];
        #pragma unroll
        for (int j = 0; j < 2; ++j){
          float arg = fmaf(vc1[j], wa.x,
                      fmaf(vc2[j], wa.y,
                      fmaf(soc[j], wa.z,
                      fmaf(ik[j],  wa.w,
                      fmaf(tk[j],  wb.x, wb.y)))));
          float r = frcp(fexp2(arg) + 1.0f);
          ra[j] = fmaf(r, wb.z, ra[j]);
        }
      }
      #pragma unroll
      for (int j = 0; j < 2; ++j){
        ra[j] += __shfl_xor(ra[j], 1, 8); ra[j] += __shfl_xor(ra[j], 2, 8); ra[j] += __shfl_xor(ra[j], 4, 8);
      }

      #pragma unroll
      for (int j = 0; j < 2; ++j){
        const float res = fmaf(-2.0f, ra[j], rb) * 0.01f;
        const float ocv = fmaf(1.2f, soc[j], 3.0f) - 0.4f * fexp2(-17.312340490667562f * soc[j]);
        const float Vp  = ocv - R0[j] * ik[j] - vc1[j] - vc2[j] + res;

        // stage outputs for step k (pre-update state), one role each
        float vA = (o==0) ? Vp
                 : (o==1) ? R0[j] : (o==2) ? R1[j] : (o==3) ? C1[j]
                 : (o==4) ? R2[j] : (o==5) ? C2[j]
                 : (o==6) ? vc1[j] : vc2[j];
        ws[baseA[j] + kk*strA] = vA;
        ws[baseB[j] + kk*strB] = soc[j];   // only meaningful for o==0 (S2)

        // RK4 on the affine ODE
        const float A1 = ik[j] * frcp(C1[j]);
        const float A2 = ik[j] * frcp(C2[j]);
        const float K1 = frcp(R1[j] * C1[j]);
        const float K2 = frcp(R2[j] * C2[j]);

        float s1 = A1 - K1 * vc1[j];
        float s2 = A1 - K1 * fmaf(0.5f, s1, vc1[j]);
        float s3 = A1 - K1 * fmaf(0.5f, s2, vc1[j]);
        float s4 = A1 - K1 * (vc1[j] + s3);
        vc1[j] = vc1[j] + (1.0f/6.0f) * (s1 + 2.0f*s2 + 2.0f*s3 + s4);

        float u1 = A2 - K2 * vc2[j];
        float u2 = A2 - K2 * fmaf(0.5f, u1, vc2[j]);
        float u3 = A2 - K2 * fmaf(0.5f, u2, vc2[j]);
        float u4 = A2 - K2 * (vc2[j] + u3);
        vc2[j] = vc2[j] + (1.0f/6.0f) * (u1 + 2.0f*u2 + 2.0f*u3 + u4);

        soc[j] = soc[j] - ik[j] * (1.0f/10800.0f);
        soc[j] = fminf(fmaxf(soc[j], 0.0f), 1.0f);
      }
    }
    __builtin_amdgcn_wave_barrier();

    // ---- writeback (non-temporal, contiguous per battery)
    // V: 64 float4 (16 bat x 4)
    {
      int bw = lane >> 2, sub = lane & 3;
      vf4 v = *(vf4*)&ws[OFF_V + bw*20 + sub*4];
      nt_store4(gV + (size_t)(wbase + bw)*H_STEPS + c0 + sub*4, v);
    }
    // P: 320 float4 (16 bat x 20)
    #pragma unroll
    for (int r = 0; r < 5; ++r){
      int s = lane + r*64;
      int bw = s / 20, sub = s % 20;
      vf4 v = *(vf4*)&ws[OFF_P + bw*84 + sub*4];
      nt_store4(gP + (size_t)(wbase + bw)*H_STEPS*5 + (size_t)c0*5 + sub*4, v);
    }
    // S: 192 float4 (16 bat x 12)
    #pragma unroll
    for (int r = 0; r < 3; ++r){
      int s = lane + r*64;
      int bw = s / 12, sub = s % 12;
      vf4 v = *(vf4*)&ws[OFF_S + bw*52 + sub*4];
      nt_store4(gS + (size_t)(wbase + bw)*H_STEPS*3 + (size_t)c0*3 + sub*4, v);
    }
    __builtin_amdgcn_wave_barrier();
  }
}

extern "C" void kernel_launch(void* const* d_in, const int* in_sizes, int n_in,
                              void* d_out, int out_size, void* d_ws, size_t ws_size,
                              hipStream_t stream)
{
  // setup_inputs order: V, I, Tz, soc0, W1, b1, W2, b2, Wr1, br1, Wr2, br2
  const float* gI   = (const float*)d_in[1];
  const float* gT   = (const float*)d_in[2];
  const float* gs0  = (const float*)d_in[3];
  const float* gW1  = (const float*)d_in[4];
  const float* gb1  = (const float*)d_in[5];
  const float* gW2  = (const float*)d_in[6];
  const float* gb2  = (const float*)d_in[7];
  const float* gWr1 = (const float*)d_in[8];
  const float* gbr1 = (const float*)d_in[9];
  const float* gWr2 = (const float*)d_in[10];
  const float* gbr2 = (const float*)d_in[11];

  float* gV = (float*)d_out;                                  // (B,H)
  float* gP = gV + (size_t)B_TOT * H_STEPS;                   // (B,H,5)
  float* gS = gP + (size_t)B_TOT * H_STEPS * 5;               // (B,H,3)

  // 8 lanes per battery-pair (T=8, G=2): 16 batteries/wave, 64/block
  dim3 grid(B_TOT / 64);   // 512 blocks -> 2 blocks/CU, 2 waves/SIMD
  dim3 block(256);
  hipLaunchKernelGGL(dcir_node_kernel, grid, block, 0, stream,
                     gI, gT, gs0, gW1, gb1, gW2, gb2, gWr1, gbr1, gWr2, gbr2,
                     gV, gP, gS);
}